// Round 1
// baseline (155.791 us; speedup 1.0000x reference)
//
#include <hip/hip_runtime.h>

#define BIGF 1e10f
#define HH 256
#define WW 256
#define BB 4
#define NPIX (BB * HH * WW)
#define GRID 256            // == #CUs: 1 block/CU, all co-resident (launch_bounds 1024,4)
#define NBINS 8
#define ACC_STRIDE 8        // doubles: 64 B apart -> distinct L2 lines
#define MAGIC 0x5F3A9C71u   // multi-byte value: cannot alias a byte-pattern ws poison

// ws layout (bytes):
//   [0 .. 511]      double acc bins, one per 64 B
//   [512 .. 515]    unsigned done-counter
//   [1024 .. 2047]  unsigned ready[256] : per-block mask-publish flags
//   [2048 .. +64K)  u32 gmask[2][BB][HH][8] : fg bit-masks, bit x of row y
#define WS_ACC_OFF 0
#define WS_CNT_OFF 512
#define WS_RDY_OFF 1024
#define WS_MASK_OFF 2048

// Exact 1D distance^2 along a row to the nearest bit of class (mask ^ iv),
// from position x. 8 u32 words per row in LDS; near-uniform addresses per wave.
__device__ inline float row_d2(const unsigned* __restrict__ rm, int x, unsigned iv) {
    int wx = x >> 5, bx = x & 31;
    int dl = 1 << 20, dr = 1 << 20;
    unsigned m0 = rm[wx] ^ iv;                    // shared by both directions
    unsigned t = m0 & (0xFFFFFFFFu >> (31 - bx)); // bits <= bx
    int w = wx;
    while (true) {
        if (t) { int p = (w << 5) + 31 - __builtin_clz(t); dl = x - p; break; }
        if (--w < 0) break;
        t = rm[w] ^ iv;
    }
    t = m0 & (0xFFFFFFFFu << bx);                 // bits >= bx
    w = wx;
    while (true) {
        if (t) { int p = (w << 5) + __builtin_ctz(t); dr = p - x; break; }
        if (++w > 7) break;
        t = rm[w] ^ iv;
    }
    int d = dl < dr ? dl : dr;
    return (d > 255) ? BIGF : (float)(d * d);
}

// Exact expanding-window min-plus along the column; candidate rows' row-dist^2
// computed on demand by bit scan. Skipped candidates satisfy fl(f+s^2) >= s^2 >= best.
__device__ inline float col_min(const unsigned* __restrict__ mb, int y, int x, unsigned iv) {
    float best = row_d2(mb + y * 8, x, iv);
    #pragma unroll 1
    for (int s = 1; s < HH; ++s) {
        float ss = (float)(s * s);
        if (ss >= best) break;
        int ym = y - s, yp = y + s;
        if (ym >= 0) best = fminf(best, row_d2(mb + ym * 8, x, iv) + ss);
        if (yp < HH) best = fminf(best, row_d2(mb + yp * 8, x, iv) + ss);
    }
    return best;
}

// Fused kernel: phase 1 builds packed fg masks (each block: 8 rows, 2 waves/row,
// one memory-latency round), device-scope flag handshake (produce-before-spin =>
// deadlock-free at 1 block/CU), phase 2 = staged-mask fused loss + reduce.
__launch_bounds__(1024, 4)
__global__ void hdt_fused_kernel(const float* __restrict__ pred,
                                 const float* __restrict__ tgt,
                                 unsigned* __restrict__ gmask,
                                 unsigned* __restrict__ ready,
                                 double* __restrict__ acc,
                                 unsigned* __restrict__ cnt,
                                 float* __restrict__ out) {
    int blk = blockIdx.x;          // b*64 + (tile/build index)
    int b = blk >> 6;
    int tid = threadIdx.x;
    int w = tid >> 6, lane = tid & 63;

    // ---- Phase 1: build 8 of this batch's 512 mask rows (2 imgs x 256 rows).
    // Wave w: row (blk&63)*8 + (w>>1), half (w&1). 2 coalesced loads + 2 ballots.
    {
        int r = ((blk & 63) << 3) + (w >> 1);   // row within batch: 0..511
        int img = r >> 8, y = r & 255, half = w & 1;
        const float* src = (img ? tgt : pred) + (b * HH + y) * WW + half * 128 + lane;
        unsigned long long b0 = __ballot(src[0] > 0.5f);
        unsigned long long b1 = __ballot(src[64] > 0.5f);
        if (lane == 0) {
            *(uint4*)(gmask + ((img * BB + b) * HH + y) * 8 + half * 4) =
                make_uint4((unsigned)b0, (unsigned)(b0 >> 32),
                           (unsigned)b1, (unsigned)(b1 >> 32));
        }
    }
    __syncthreads();               // all mask stores drained (vmcnt(0) before barrier)
    if (tid == 0) {
        if (blk == 0) {            // acc/cnt init ordered before blk0's flag;
            #pragma unroll         // consumers' atomics come after observing ALL flags
            for (int i = 0; i < NBINS; ++i) acc[i * ACC_STRIDE] = 0.0;
            *cnt = 0u;
        }
        __threadfence();           // agent release: buffer_wbl2 -> cross-XCD visible
        __hip_atomic_store(&ready[blk], MAGIC, __ATOMIC_RELEASE,
                           __HIP_MEMORY_SCOPE_AGENT);
    }

    // ---- Gate: every thread acquire-polls a flag (4 threads/flag), so every
    // thread's later gmask reads are ordered after the producers' releases.
    while (__hip_atomic_load(&ready[tid & (GRID - 1)], __ATOMIC_ACQUIRE,
                             __HIP_MEMORY_SCOPE_AGENT) != MAGIC)
        __builtin_amdgcn_s_sleep(2);
    __syncthreads();

    // ---- Phase 2: stage this batch's masks (1 uint4/thread, linear LDS order),
    // empty-fg flags from staged words, fused loss + block reduce + binned atomics.
    __shared__ __align__(16) unsigned lmask[2][HH][8];   // 16 KB
    __shared__ unsigned wfl[16];
    __shared__ float wsum[16];
    {
        int img = tid >> 9;
        int row = (tid >> 1) & 255;
        int half = tid & 1;
        const uint4* gp = (const uint4*)gmask;
        uint4 a = gp[((img * BB + b) * HH + row) * 2 + half];
        ((uint4*)lmask)[tid] = a;
        unsigned onz = a.x | a.y | a.z | a.w;
        unsigned long long bal = __ballot(onz != 0u);    // waves 0-7: img0, 8-15: img1
        if ((tid & 63) == 0) wfl[tid >> 6] = (bal != 0ULL) ? 1u : 0u;
    }
    __syncthreads();
    unsigned fl_p = wfl[0] | wfl[1] | wfl[2] | wfl[3] | wfl[4] | wfl[5] | wfl[6] | wfl[7];
    unsigned fl_t = wfl[8] | wfl[9] | wfl[10] | wfl[11] | wfl[12] | wfl[13] | wfl[14] | wfl[15];

    int x = tid & (WW - 1);
    int y = ((blk & 63) << 2) + (tid >> 8);   // wave-uniform row, 4-row tile
    int idx = (b * HH + y) * WW + x;
    float pv = pred[idx], tv = tgt[idx];
    float e = pv - tv;
    float errsq = e * e;
    float d2p = 0.0f, d2t = 0.0f;
    if (fl_p) {
        // query class fg -> scan for bg (invert); bg -> scan for fg
        unsigned iv = (pv > 0.5f) ? 0xFFFFFFFFu : 0u;
        float best = col_min(&lmask[0][0][0], y, x, iv);
        float dt = sqrtf(fminf(best, BIGF));  // match reference: sqrt then square
        d2p = dt * dt;
    }
    if (fl_t) {
        unsigned iv = (tv > 0.5f) ? 0xFFFFFFFFu : 0u;
        float best = col_min(&lmask[1][0][0], y, x, iv);
        float dt = sqrtf(fminf(best, BIGF));
        d2t = dt * dt;
    }
    float lsum = errsq * (d2p + d2t);

    // block reduce: wave64 shuffle then LDS across 16 waves
    #pragma unroll
    for (int off = 32; off > 0; off >>= 1)
        lsum += __shfl_down(lsum, off, 64);
    if ((tid & 63) == 0) wsum[tid >> 6] = lsum;
    __syncthreads();
    if (tid == 0) {
        float s2 = 0.0f;
        #pragma unroll
        for (int i = 0; i < 16; ++i) s2 += wsum[i];
        atomicAdd(&acc[(blk & (NBINS - 1)) * ACC_STRIDE], (double)s2);
        __threadfence();
        if (atomicAdd(cnt, 1u) == GRID - 1) {
            double v = 0.0;
            #pragma unroll
            for (int i = 0; i < NBINS; ++i)
                v += atomicAdd(&acc[i * ACC_STRIDE], 0.0);  // device-coherent reads
            out[0] = (float)(v * (1.0 / (double)NPIX));
        }
    }
}

extern "C" void kernel_launch(void* const* d_in, const int* in_sizes, int n_in,
                              void* d_out, int out_size, void* d_ws, size_t ws_size,
                              hipStream_t stream) {
    const float* pred = (const float*)d_in[0];
    const float* tgt = (const float*)d_in[1];
    float* out = (float*)d_out;
    char* ws = (char*)d_ws;
    double* acc = (double*)(ws + WS_ACC_OFF);
    unsigned* cnt = (unsigned*)(ws + WS_CNT_OFF);
    unsigned* ready = (unsigned*)(ws + WS_RDY_OFF);
    unsigned* gmask = (unsigned*)(ws + WS_MASK_OFF);

    hdt_fused_kernel<<<GRID, 1024, 0, stream>>>(pred, tgt, gmask, ready, acc, cnt, out);
}

// Round 2
// 68.546 us; speedup vs baseline: 2.2728x; 2.2728x over previous
//
#include <hip/hip_runtime.h>

#define BIGF 1e10f
#define HH 256
#define WW 256
#define BB 4
#define NPIX (BB * HH * WW)
#define GRID 256            // == #CUs: 1 block/CU, all co-resident (launch_bounds 1024,4)
#define NBINS 8
#define ACC_STRIDE 8        // doubles: 64 B apart -> distinct L2 lines
#define MAGIC 0x5F3A9C71u   // multi-byte value: cannot alias a byte-pattern ws poison

// ws layout (bytes):
//   [0 .. 511]      double acc bins, one per 64 B
//   [512 .. 515]    unsigned done-counter
//   [1024 .. 2047]  unsigned ready[256] : per-block mask-publish flags
//   [2048 .. +64K)  u32 gmask[2][BB][HH][8] : fg bit-masks, bit x of row y
#define WS_ACC_OFF 0
#define WS_CNT_OFF 512
#define WS_RDY_OFF 1024
#define WS_MASK_OFF 2048

#define LOAD_RLX(p)     __hip_atomic_load((p), __ATOMIC_RELAXED, __HIP_MEMORY_SCOPE_AGENT)
#define STORE_RLX(p, v) __hip_atomic_store((p), (v), __ATOMIC_RELAXED, __HIP_MEMORY_SCOPE_AGENT)

// Exact 1D distance^2 along a row to the nearest bit of class (mask ^ iv),
// from position x. 8 u32 words per row in LDS; near-uniform addresses per wave.
__device__ inline float row_d2(const unsigned* __restrict__ rm, int x, unsigned iv) {
    int wx = x >> 5, bx = x & 31;
    int dl = 1 << 20, dr = 1 << 20;
    unsigned m0 = rm[wx] ^ iv;                    // shared by both directions
    unsigned t = m0 & (0xFFFFFFFFu >> (31 - bx)); // bits <= bx
    int w = wx;
    while (true) {
        if (t) { int p = (w << 5) + 31 - __builtin_clz(t); dl = x - p; break; }
        if (--w < 0) break;
        t = rm[w] ^ iv;
    }
    t = m0 & (0xFFFFFFFFu << bx);                 // bits >= bx
    w = wx;
    while (true) {
        if (t) { int p = (w << 5) + __builtin_ctz(t); dr = p - x; break; }
        if (++w > 7) break;
        t = rm[w] ^ iv;
    }
    int d = dl < dr ? dl : dr;
    return (d > 255) ? BIGF : (float)(d * d);
}

// Exact expanding-window min-plus along the column; candidate rows' row-dist^2
// computed on demand by bit scan. Skipped candidates satisfy fl(f+s^2) >= s^2 >= best.
__device__ inline float col_min(const unsigned* __restrict__ mb, int y, int x, unsigned iv) {
    float best = row_d2(mb + y * 8, x, iv);
    #pragma unroll 1
    for (int s = 1; s < HH; ++s) {
        float ss = (float)(s * s);
        if (ss >= best) break;
        int ym = y - s, yp = y + s;
        if (ym >= 0) best = fminf(best, row_d2(mb + ym * 8, x, iv) + ss);
        if (yp < HH) best = fminf(best, row_d2(mb + yp * 8, x, iv) + ss);
    }
    return best;
}

// Fused kernel, manual-coherence handshake: ALL cross-block traffic uses
// relaxed agent-scope atomics (global_load/store sc1 -> coherence point,
// NO buffer_inv / buffer_wbl2 cache maintenance -- round-1's 2.3 GB refetch
// storm came from an acquire load in the spin loop).
__launch_bounds__(1024, 4)
__global__ void hdt_fused_kernel(const float* __restrict__ pred,
                                 const float* __restrict__ tgt,
                                 unsigned* __restrict__ gmask,
                                 unsigned* __restrict__ ready,
                                 double* __restrict__ acc,
                                 unsigned* __restrict__ cnt,
                                 float* __restrict__ out) {
    int blk = blockIdx.x;          // b*64 + (tile/build index)
    int b = blk >> 6;
    int tid = threadIdx.x;
    int w = tid >> 6, lane = tid & 63;

    // ---- Phase 1: build 8 of this batch's 512 mask rows (2 imgs x 256 rows).
    // Wave w: row (blk&63)*8 + (w>>1), half (w&1). 2 coalesced loads + 2 ballots,
    // lane 0 publishes the two ballot u64s write-through (sc1).
    {
        int r = ((blk & 63) << 3) + (w >> 1);   // row within batch: 0..511
        int img = r >> 8, y = r & 255, half = w & 1;
        const float* src = (img ? tgt : pred) + (b * HH + y) * WW + half * 128 + lane;
        unsigned long long b0 = __ballot(src[0] > 0.5f);
        unsigned long long b1 = __ballot(src[64] > 0.5f);
        if (lane == 0) {
            unsigned long long* dst = (unsigned long long*)
                (gmask + ((img * BB + b) * HH + y) * 8 + half * 4);
            STORE_RLX(dst, b0);       // words {0,1} of the half-row
            STORE_RLX(dst + 1, b1);   // words {2,3}
        }
    }
    if (blk == 0 && tid == 0) {       // init ordered before blk0's flag by the
        #pragma unroll                // vmcnt(0) drain at the barrier below
        for (int i = 0; i < NBINS; ++i) STORE_RLX(&acc[i * ACC_STRIDE], 0.0);
        STORE_RLX(cnt, 0u);
    }
    __syncthreads();                  // s_waitcnt vmcnt(0): all sc1 stores ACKed
    if (tid == 0) STORE_RLX(&ready[blk], MAGIC);   // relaxed publish: no wbl2

    // ---- Gate: threads 0..255 each poll ONE flag with a relaxed (sc1) load --
    // no per-poll cache invalidate. Produce-before-spin => deadlock-free at
    // 1 block/CU full co-residency.
    if (tid < GRID) {
        while (LOAD_RLX(&ready[tid]) != MAGIC)
            __builtin_amdgcn_s_sleep(4);
    }
    __syncthreads();

    // ---- Phase 2: stage this batch's masks (2 x u64 sc1 loads/thread, linear
    // LDS order), empty-fg flags from staged words, fused loss + block reduce.
    __shared__ __align__(16) unsigned lmask[2][HH][8];   // 16 KB
    __shared__ unsigned wfl[16];
    __shared__ float wsum[16];
    {
        int img = tid >> 9;
        int row = (tid >> 1) & 255;
        int half = tid & 1;
        const unsigned long long* gp = (const unsigned long long*)
            (gmask + ((img * BB + b) * HH + row) * 8 + half * 4);
        unsigned long long v0 = LOAD_RLX(gp);
        unsigned long long v1 = LOAD_RLX(gp + 1);
        uint4 a = make_uint4((unsigned)v0, (unsigned)(v0 >> 32),
                             (unsigned)v1, (unsigned)(v1 >> 32));
        ((uint4*)lmask)[tid] = a;
        unsigned onz = a.x | a.y | a.z | a.w;
        unsigned long long bal = __ballot(onz != 0u);    // waves 0-7: img0, 8-15: img1
        if ((tid & 63) == 0) wfl[tid >> 6] = (bal != 0ULL) ? 1u : 0u;
    }
    __syncthreads();
    unsigned fl_p = wfl[0] | wfl[1] | wfl[2] | wfl[3] | wfl[4] | wfl[5] | wfl[6] | wfl[7];
    unsigned fl_t = wfl[8] | wfl[9] | wfl[10] | wfl[11] | wfl[12] | wfl[13] | wfl[14] | wfl[15];

    int x = tid & (WW - 1);
    int y = ((blk & 63) << 2) + (tid >> 8);   // wave-uniform row, 4-row tile
    int idx = (b * HH + y) * WW + x;
    float pv = pred[idx], tv = tgt[idx];
    float e = pv - tv;
    float errsq = e * e;
    float d2p = 0.0f, d2t = 0.0f;
    if (fl_p) {
        // query class fg -> scan for bg (invert); bg -> scan for fg
        unsigned iv = (pv > 0.5f) ? 0xFFFFFFFFu : 0u;
        float best = col_min(&lmask[0][0][0], y, x, iv);
        float dt = sqrtf(fminf(best, BIGF));  // match reference: sqrt then square
        d2p = dt * dt;
    }
    if (fl_t) {
        unsigned iv = (tv > 0.5f) ? 0xFFFFFFFFu : 0u;
        float best = col_min(&lmask[1][0][0], y, x, iv);
        float dt = sqrtf(fminf(best, BIGF));
        d2t = dt * dt;
    }
    float lsum = errsq * (d2p + d2t);

    // block reduce: wave64 shuffle then LDS across 16 waves
    #pragma unroll
    for (int off = 32; off > 0; off >>= 1)
        lsum += __shfl_down(lsum, off, 64);
    if ((tid & 63) == 0) wsum[tid >> 6] = lsum;
    __syncthreads();
    if (tid == 0) {
        float s2 = 0.0f;
        #pragma unroll
        for (int i = 0; i < 16; ++i) s2 += wsum[i];
        atomicAdd(&acc[(blk & (NBINS - 1)) * ACC_STRIDE], (double)s2);
        // order acc-add before cnt-add without __threadfence (wbl2+inv on gfx950):
        asm volatile("s_waitcnt vmcnt(0)" ::: "memory");
        if (atomicAdd(cnt, 1u) == GRID - 1) {
            double v = 0.0;
            #pragma unroll
            for (int i = 0; i < NBINS; ++i)
                v += atomicAdd(&acc[i * ACC_STRIDE], 0.0);  // coherence-point reads
            out[0] = (float)(v * (1.0 / (double)NPIX));
        }
    }
}

extern "C" void kernel_launch(void* const* d_in, const int* in_sizes, int n_in,
                              void* d_out, int out_size, void* d_ws, size_t ws_size,
                              hipStream_t stream) {
    const float* pred = (const float*)d_in[0];
    const float* tgt = (const float*)d_in[1];
    float* out = (float*)d_out;
    char* ws = (char*)d_ws;
    double* acc = (double*)(ws + WS_ACC_OFF);
    unsigned* cnt = (unsigned*)(ws + WS_CNT_OFF);
    unsigned* ready = (unsigned*)(ws + WS_RDY_OFF);
    unsigned* gmask = (unsigned*)(ws + WS_MASK_OFF);

    hdt_fused_kernel<<<GRID, 1024, 0, stream>>>(pred, tgt, gmask, ready, acc, cnt, out);
}